// Round 1
// baseline (817.314 us; speedup 1.0000x reference)
//
#include <hip/hip_runtime.h>
#include <stdint.h>

// HashGrid3D: L=16 levels, T=2^19 entries/level, F=2 features, trilinear interp.
// One thread per point; full unroll over levels so all 128 gathers are
// independent and can be kept in flight by the compiler.

constexpr int   LVL   = 16;
constexpr int   TBL   = 524288;          // 2^19
constexpr uint32_t TMASK = 0x7FFFFu;     // T-1
constexpr uint32_t P2 = 2654435761u;
constexpr uint32_t P3 = 805459861u;
// RES[l] = round(16 * (512/16)^(l/15)) = round(16 * 2^(l/3))
constexpr int RESV[LVL] = {16, 20, 25, 32, 40, 51, 64, 81,
                           102, 128, 161, 203, 256, 323, 406, 512};

__global__ __launch_bounds__(256)
void hashgrid3d_kernel(const float* __restrict__ xyt,
                       const float* __restrict__ tables,
                       float* __restrict__ out, int n)
{
    int p = blockIdx.x * 256 + threadIdx.x;
    if (p >= n) return;

    float x = xyt[3 * p + 0];
    float y = xyt[3 * p + 1];
    float z = xyt[3 * p + 2];

    float outv[2 * LVL];

    #pragma unroll
    for (int l = 0; l < LVL; ++l) {
        const int N = RESV[l];
        const float2* __restrict__ tbl =
            (const float2*)tables + (size_t)l * TBL;

        float sx = x * (float)N, sy = y * (float)N, sz = z * (float)N;
        float fx = floorf(sx), fy = floorf(sy), fz = floorf(sz);
        float tx = sx - fx, ty = sy - fy, tz = sz - fz;
        int ix = (int)fx, iy = (int)fy, iz = (int)fz;

        // reference applies (i0 + off) % N to every corner; i0 can hit N on
        // the fp rounding edge, so wrap corner 0 too.
        int ix0 = (ix >= N) ? ix - N : ix;
        int iy0 = (iy >= N) ? iy - N : iy;
        int iz0 = (iz >= N) ? iz - N : iz;
        int ix1 = ix + 1; ix1 = (ix1 >= N) ? ix1 - N : ix1;
        int iy1 = iy + 1; iy1 = (iy1 >= N) ? iy1 - N : iy1;
        int iz1 = iz + 1; iz1 = (iz1 >= N) ? iz1 - N : iz1;

        uint32_t hx0 = (uint32_t)ix0;           // prime 1
        uint32_t hx1 = (uint32_t)ix1;
        uint32_t hy0 = (uint32_t)iy0 * P2;
        uint32_t hy1 = (uint32_t)iy1 * P2;
        uint32_t hz0 = (uint32_t)iz0 * P3;
        uint32_t hz1 = (uint32_t)iz1 * P3;

        float2 g000 = tbl[(hx0 ^ hy0 ^ hz0) & TMASK];
        float2 g100 = tbl[(hx1 ^ hy0 ^ hz0) & TMASK];
        float2 g010 = tbl[(hx0 ^ hy1 ^ hz0) & TMASK];
        float2 g110 = tbl[(hx1 ^ hy1 ^ hz0) & TMASK];
        float2 g001 = tbl[(hx0 ^ hy0 ^ hz1) & TMASK];
        float2 g101 = tbl[(hx1 ^ hy0 ^ hz1) & TMASK];
        float2 g011 = tbl[(hx0 ^ hy1 ^ hz1) & TMASK];
        float2 g111 = tbl[(hx1 ^ hy1 ^ hz1) & TMASK];

        float wx1 = tx, wx0 = 1.0f - tx;
        float wy1 = ty, wy0 = 1.0f - ty;
        float wz1 = tz, wz0 = 1.0f - tz;
        float wz0y0 = wy0 * wz0, wz0y1 = wy1 * wz0;
        float wz1y0 = wy0 * wz1, wz1y1 = wy1 * wz1;
        float w000 = wx0 * wz0y0, w100 = wx1 * wz0y0;
        float w010 = wx0 * wz0y1, w110 = wx1 * wz0y1;
        float w001 = wx0 * wz1y0, w101 = wx1 * wz1y0;
        float w011 = wx0 * wz1y1, w111 = wx1 * wz1y1;

        float f0 = w000 * g000.x + w100 * g100.x + w010 * g010.x + w110 * g110.x
                 + w001 * g001.x + w101 * g101.x + w011 * g011.x + w111 * g111.x;
        float f1 = w000 * g000.y + w100 * g100.y + w010 * g010.y + w110 * g110.y
                 + w001 * g001.y + w101 * g101.y + w011 * g011.y + w111 * g111.y;

        outv[2 * l + 0] = f0;
        outv[2 * l + 1] = f1;
    }

    // 128 B contiguous per thread, 8 x float4 stores (16 B aligned: p*32 floats)
    float4* o = (float4*)(out + (size_t)p * 32);
    #pragma unroll
    for (int i = 0; i < 8; ++i)
        o[i] = ((const float4*)outv)[i];
}

extern "C" void kernel_launch(void* const* d_in, const int* in_sizes, int n_in,
                              void* d_out, int out_size, void* d_ws, size_t ws_size,
                              hipStream_t stream) {
    const float* xyt    = (const float*)d_in[0];   // (1048576, 3) f32
    const float* tables = (const float*)d_in[1];   // (16, 524288, 2) f32
    float* out = (float*)d_out;                    // (1048576, 32) f32
    int n = in_sizes[0] / 3;
    int blocks = (n + 255) / 256;
    hashgrid3d_kernel<<<blocks, 256, 0, stream>>>(xyt, tables, out, n);
}